// Round 1
// baseline (286.532 us; speedup 1.0000x reference)
//
#include <hip/hip_runtime.h>

// Laplacian pyramid L1 loss, (32,3,512,512) fp32, 5 levels.
// pyramid(in)-pyramid(tg) == pyramid(in-tg) (linearity) -> one pyramid.
// upsample(conv 4K on zero-stuffed) == polyphase on down:
//   even phase taps (.125,.75,.125), odd phase (.5,.5) per axis.
// lap_slide: wave-owned line-sliding pipeline. One wave = one R-row strip.
// Lane owns NC=W/64 cols. Horizontal 5-tap via shuffles, vertical via 5-row
// register ring, up via 3-row W ring. Band rows come from a 3-row raw-row
// register ring (NO global re-read). Next iteration's rows are prefetched
// (raw A/B regs) one full iteration ahead -> load latency hidden by compute.
// R halved vs prior version (16/8/4 -> 8/4/2): grid 3072 -> 6144 waves
// (24 waves/CU, matches the 6-wave/SIMD VGPR budget) -- the prior version
// was grid-starved (Occupancy 27%, VALUBusy 14%, HBM 25%): latency-bound.
// Halo re-reads from smaller strips are L2/L3-absorbed (strips of one plane
// are consecutive in sid -> temporal locality).
// lap_small: levels 3+4, one 1024-thr block per plane.

#define BC 96
#define KA 0.0625f
#define KB 0.25f
#define KC 0.375f

__device__ __forceinline__ int refl(int i, int n) {
    if (i < 0) i = -i;
    if (i >= n) i = 2 * n - 2 - i;
    return i;
}

// raw row load: A into a[], B into b[] (DIFF only). No subtraction here.
template<int H, int NC, bool DIFF>
__device__ __forceinline__ void load_raw(const float* __restrict__ pa,
                                         const float* __restrict__ pb,
                                         int r, int basec,
                                         float* __restrict__ a,
                                         float* __restrict__ b) {
    const int off = r * H + basec;
    if constexpr (NC == 8) {
        float4 a0 = *(const float4*)(pa + off);
        float4 a1 = *(const float4*)(pa + off + 4);
        a[0]=a0.x; a[1]=a0.y; a[2]=a0.z; a[3]=a0.w;
        a[4]=a1.x; a[5]=a1.y; a[6]=a1.z; a[7]=a1.w;
        if constexpr (DIFF) {
            float4 b0 = *(const float4*)(pb + off);
            float4 b1 = *(const float4*)(pb + off + 4);
            b[0]=b0.x; b[1]=b0.y; b[2]=b0.z; b[3]=b0.w;
            b[4]=b1.x; b[5]=b1.y; b[6]=b1.z; b[7]=b1.w;
        }
    } else if constexpr (NC == 4) {
        float4 a0 = *(const float4*)(pa + off);
        a[0]=a0.x; a[1]=a0.y; a[2]=a0.z; a[3]=a0.w;
        if constexpr (DIFF) {
            float4 b0 = *(const float4*)(pb + off);
            b[0]=b0.x; b[1]=b0.y; b[2]=b0.z; b[3]=b0.w;
        }
    } else {
        float2 a0 = *(const float2*)(pa + off);
        a[0]=a0.x; a[1]=a0.y;
        if constexpr (DIFF) {
            float2 b0 = *(const float2*)(pb + off);
            b[0]=b0.x; b[1]=b0.y;
        }
    }
}

template<int NC, bool DIFF>
__device__ __forceinline__ void materialize(const float* __restrict__ a,
                                            const float* __restrict__ b,
                                            float* __restrict__ c) {
#pragma unroll
    for (int i = 0; i < NC; ++i) c[i] = DIFF ? (a[i] - b[i]) : a[i];
}

// horizontal 5-tap at even cols. c = own NC cols; o = ND outputs.
template<int NC>
__device__ __forceinline__ void hconv(const float* __restrict__ c,
                                      float* __restrict__ o, int lane) {
    constexpr int ND = NC / 2;
    float e[NC + 3];
#pragma unroll
    for (int i = 0; i < NC; ++i) e[i + 2] = c[i];
    const bool l0 = (lane == 0), l63 = (lane == 63);
    { float v = __shfl(e[NC + 1], lane - 1); e[1] = l0 ? e[3] : v; }
    if constexpr (NC >= 4) {
        { float v = __shfl(e[NC], lane - 1); e[0] = l0 ? e[4] : v; }
        { float v = __shfl(e[2], lane + 1); e[NC + 2] = l63 ? e[NC] : v; }
    } else {
        e[0] = __shfl(e[2], l0 ? 1 : lane - 1);
        e[NC + 2] = __shfl(e[2], l63 ? 63 : lane + 1);
    }
#pragma unroll
    for (int j = 0; j < ND; ++j)
        o[j] = KA * e[2*j] + KB * e[2*j+1] + KC * e[2*j+2]
             + KB * e[2*j+3] + KA * e[2*j+4];
}

template<int H, int NC, bool DIFF, int R>
__global__ __launch_bounds__(256) void lap_slide(
        const float* __restrict__ A, const float* __restrict__ B,
        float* __restrict__ down, float* __restrict__ out, float invN) {
    constexpr int Hd = H / 2, ND = NC / 2, SPP = H / R;
    __shared__ float red[4];
    const int tid = threadIdx.x;
    const int lane = tid & 63, wid = tid >> 6;
    const int sid = blockIdx.x * 4 + wid;
    const int bc = sid / SPP;
    const int y0 = (sid % SPP) * R;
    const float* pa = A + (size_t)bc * H * H;
    const float* pb = DIFF ? (B + (size_t)bc * H * H) : nullptr;
    float* pd = down + (size_t)bc * Hd * Hd;
    const int basec = lane * NC;

    float h0[ND], h1[ND], h2[ND], h3[ND], h4[ND];
    float w0[NC], w1[NC], w2[NC];
    float eOld[NC], eMid[NC], oPrev[NC];      // raw-row ring for band
    float nA1[NC], nB1[NC], nA2[NC], nB2[NC]; // prefetch regs
    float c1[NC], c2[NC], t[NC], tb[NC];
#pragma unroll
    for (int i = 0; i < NC; ++i) {
        w0[i] = 0.f; w1[i] = 0.f; w2[i] = 0.f;
        eOld[i] = 0.f; oPrev[i] = 0.f;
    }
    float acc = 0.f;

    const int d0 = y0 >> 1;
    int dbeg = d0 - 1; if (dbeg < 0) dbeg = 0;
    const int dend = d0 + R / 2;

    // prologue: rows 2dbeg-2, 2dbeg-1, 2dbeg
    load_raw<H,NC,DIFF>(pa, pb, refl(2*dbeg - 2, H), basec, t, tb);
    materialize<NC,DIFF>(t, tb, c1); hconv<NC>(c1, h0, lane);
    load_raw<H,NC,DIFF>(pa, pb, refl(2*dbeg - 1, H), basec, t, tb);
    materialize<NC,DIFF>(t, tb, c1); hconv<NC>(c1, h1, lane);
    load_raw<H,NC,DIFF>(pa, pb, refl(2*dbeg, H), basec, t, tb);
    materialize<NC,DIFF>(t, tb, eMid); hconv<NC>(eMid, h2, lane);
    // prefetch rows for d = dbeg
    load_raw<H,NC,DIFF>(pa, pb, refl(2*dbeg + 1, H), basec, nA1, nB1);
    load_raw<H,NC,DIFF>(pa, pb, refl(2*dbeg + 2, H), basec, nA2, nB2);

    for (int d = dbeg; d <= dend; ++d) {
        // materialize current rows, then immediately issue next-iter loads
        materialize<NC,DIFF>(nA1, nB1, c1);
        materialize<NC,DIFF>(nA2, nB2, c2);
        load_raw<H,NC,DIFF>(pa, pb, refl(2*d + 3, H), basec, nA1, nB1);
        load_raw<H,NC,DIFF>(pa, pb, refl(2*d + 4, H), basec, nA2, nB2);

        hconv<NC>(c1, h3, lane);
        hconv<NC>(c2, h4, lane);

        float dn[ND];
#pragma unroll
        for (int j = 0; j < ND; ++j)
            dn[j] = KA*h0[j] + KB*h1[j] + KC*h2[j] + KB*h3[j] + KA*h4[j];

        if (d >= d0 && d < d0 + R/2) {
            const int doff = d * Hd + lane * ND;
            if constexpr (ND == 4) {
                float4 s; s.x=dn[0]; s.y=dn[1]; s.z=dn[2]; s.w=dn[3];
                *(float4*)(pd + doff) = s;
            } else if constexpr (ND == 2) {
                float2 s; s.x=dn[0]; s.y=dn[1];
                *(float2*)(pd + doff) = s;
            } else {
                pd[doff] = dn[0];
            }
        }

        // horizontal-up row W[d]
        float dm, dp;
        if constexpr (ND >= 2) {
            { float v = __shfl(dn[ND-1], lane - 1); dm = (lane == 0)  ? dn[1]    : v; }
            { float v = __shfl(dn[0],    lane + 1); dp = (lane == 63) ? dn[ND-1] : v; }
        } else {
            dm = __shfl(dn[0], (lane == 0)  ? 1  : lane - 1);
            dp = __shfl(dn[0], (lane == 63) ? 63 : lane + 1);
        }
#pragma unroll
        for (int i = 0; i < NC; ++i) { w0[i] = w1[i]; w1[i] = w2[i]; }
#pragma unroll
        for (int j = 0; j < ND; ++j) {
            float lf = j ? dn[j-1] : dm;
            float rg = (j + 1 < ND) ? dn[j+1] : dp;
            w2[2*j]     = 0.125f * lf + 0.75f * dn[j] + 0.125f * rg;
            w2[2*j + 1] = 0.5f * (dn[j] + rg);
        }

        // band rows 2d-2 (even, from eOld), 2d-1 (odd, from oPrev)
        if (d >= d0 + 1) {
            const int ye = 2 * d - 2;
            if (ye == 0) {
#pragma unroll
                for (int i = 0; i < NC; ++i) {
                    acc += fabsf(eOld[i]  - (0.75f*w1[i] + 0.25f*w2[i]));
                    acc += fabsf(oPrev[i] - 0.5f*(w1[i] + w2[i]));
                }
            } else if (ye == H - 2) {
#pragma unroll
                for (int i = 0; i < NC; ++i) {
                    acc += fabsf(eOld[i]  - (0.125f*w0[i] + 0.875f*w1[i]));
                    acc += fabsf(oPrev[i] - w1[i]);
                }
            } else {
#pragma unroll
                for (int i = 0; i < NC; ++i) {
                    acc += fabsf(eOld[i]  - (0.125f*w0[i] + 0.75f*w1[i] + 0.125f*w2[i]));
                    acc += fabsf(oPrev[i] - 0.5f*(w1[i] + w2[i]));
                }
            }
        }

        // shift rings
#pragma unroll
        for (int i = 0; i < NC; ++i) {
            eOld[i] = eMid[i]; eMid[i] = c2[i]; oPrev[i] = c1[i];
        }
#pragma unroll
        for (int j = 0; j < ND; ++j) { h0[j] = h2[j]; h1[j] = h3[j]; h2[j] = h4[j]; }
    }

#pragma unroll
    for (int off2 = 32; off2 > 0; off2 >>= 1)
        acc += __shfl_down(acc, off2, 64);
    if (lane == 0) red[wid] = acc;
    __syncthreads();
    if (tid == 0)
        atomicAdd(out, (red[0] + red[1] + red[2] + red[3]) * invN);
}

// ---- levels 3 (64->32) and 4 (32->16): one 1024-thr block per plane ----
__global__ __launch_bounds__(1024) void lap_small(
        const float* __restrict__ dsrc, float* __restrict__ out,
        float invN3, float invN4) {
    __shared__ float p[64 * 66];
    __shared__ float hh[64 * 34];
    __shared__ float dd[32 * 34];
    __shared__ float W3[32 * 64];
    __shared__ float h4[32 * 18];
    __shared__ float d4[16 * 18];
    __shared__ float W4[16 * 32];
    __shared__ float red[16];
    const int tid = threadIdx.x;
    const float* src = dsrc + (size_t)blockIdx.x * 4096;
    for (int i = tid; i < 4096; i += 1024)
        p[(i >> 6) * 66 + (i & 63)] = src[i];
    __syncthreads();
    const float k[5] = {KA, KB, KC, KB, KA};
    for (int i = tid; i < 64 * 32; i += 1024) {
        int r = i >> 5, t = i & 31;
        const float* pr = p + r * 66;
        float s = 0.f;
#pragma unroll
        for (int v = 0; v < 5; ++v) s += k[v] * pr[refl(2*t + v - 2, 64)];
        hh[r * 34 + t] = s;
    }
    __syncthreads();
    for (int i = tid; i < 32 * 32; i += 1024) {
        int dy = i >> 5, t = i & 31;
        float s = 0.f;
#pragma unroll
        for (int u = 0; u < 5; ++u) s += k[u] * hh[refl(2*dy + u - 2, 64) * 34 + t];
        dd[dy * 34 + t] = s;
    }
    __syncthreads();
    for (int i = tid; i < 32 * 32; i += 1024) {
        int a = i >> 5, t = i & 31;
        const float* dr = dd + a * 34;
        float dm = dr[t == 0 ? 1 : t - 1];
        float dc = dr[t];
        float dp = dr[t == 31 ? 31 : t + 1];
        W3[a * 64 + 2*t]     = 0.125f * dm + 0.75f * dc + 0.125f * dp;
        W3[a * 64 + 2*t + 1] = 0.5f * (dc + dp);
    }
    __syncthreads();
    float acc3 = 0.f;
    for (int i = tid; i < 4096; i += 1024) {
        int y = i >> 6, x = i & 63;
        float cur = p[y * 66 + x];
        float up;
        if ((y & 1) == 0) {
            int a0 = refl(y - 2, 64) >> 1, a1 = y >> 1, a2 = refl(y + 2, 64) >> 1;
            up = 0.125f*W3[a0*64 + x] + 0.75f*W3[a1*64 + x] + 0.125f*W3[a2*64 + x];
        } else {
            int a0 = (y - 1) >> 1, a1 = refl(y + 1, 64) >> 1;
            up = 0.5f * (W3[a0*64 + x] + W3[a1*64 + x]);
        }
        acc3 += fabsf(cur - up);
    }
    __syncthreads();
    for (int i = tid; i < 32 * 16; i += 1024) {
        int r = i >> 4, t = i & 15;
        const float* pr = dd + r * 34;
        float s = 0.f;
#pragma unroll
        for (int v = 0; v < 5; ++v) s += k[v] * pr[refl(2*t + v - 2, 32)];
        h4[r * 18 + t] = s;
    }
    __syncthreads();
    for (int i = tid; i < 16 * 16; i += 1024) {
        int dy = i >> 4, t = i & 15;
        float s = 0.f;
#pragma unroll
        for (int u = 0; u < 5; ++u) s += k[u] * h4[refl(2*dy + u - 2, 32) * 18 + t];
        d4[dy * 18 + t] = s;
    }
    __syncthreads();
    for (int i = tid; i < 16 * 16; i += 1024) {
        int a = i >> 4, t = i & 15;
        const float* dr = d4 + a * 18;
        float dm = dr[t == 0 ? 1 : t - 1];
        float dc = dr[t];
        float dp = dr[t == 15 ? 15 : t + 1];
        W4[a * 32 + 2*t]     = 0.125f * dm + 0.75f * dc + 0.125f * dp;
        W4[a * 32 + 2*t + 1] = 0.5f * (dc + dp);
    }
    __syncthreads();
    float acc4 = 0.f;
    for (int i = tid; i < 1024; i += 1024) {
        int y = i >> 5, x = i & 31;
        float cur = dd[y * 34 + x];
        float up;
        if ((y & 1) == 0) {
            int a0 = refl(y - 2, 32) >> 1, a1 = y >> 1, a2 = refl(y + 2, 32) >> 1;
            up = 0.125f*W4[a0*32 + x] + 0.75f*W4[a1*32 + x] + 0.125f*W4[a2*32 + x];
        } else {
            int a0 = (y - 1) >> 1, a1 = refl(y + 1, 32) >> 1;
            up = 0.5f * (W4[a0*32 + x] + W4[a1*32 + x]);
        }
        acc4 += fabsf(cur - up);
    }
    float acc = acc3 * invN3 + acc4 * invN4;
#pragma unroll
    for (int off2 = 32; off2 > 0; off2 >>= 1)
        acc += __shfl_down(acc, off2, 64);
    int lane = tid & 63, wid = tid >> 6;
    if (lane == 0) red[wid] = acc;
    __syncthreads();
    if (tid == 0) {
        float s = 0.f;
#pragma unroll
        for (int i = 0; i < 16; ++i) s += red[i];
        atomicAdd(out, s);
    }
}

extern "C" void kernel_launch(void* const* d_in, const int* in_sizes, int n_in,
                              void* d_out, int out_size, void* d_ws, size_t ws_size,
                              hipStream_t stream) {
    const float* in = (const float*)d_in[0];
    const float* tg = (const float*)d_in[1];
    float* out = (float*)d_out;
    float* ws = (float*)d_ws;

    float* down0 = ws;                                   // 96*256*256
    float* down1 = down0 + (size_t)BC * 256 * 256;       // 96*128*128
    float* down2 = down1 + (size_t)BC * 128 * 128;       // 96*64*64

    hipMemsetAsync(out, 0, sizeof(float), stream);

    // level 0: R=8 -> 96*64 strips (6144 waves, 24/CU)
    lap_slide<512, 8, true, 8><<<96 * 64 / 4, 256, 0, stream>>>(
        in, tg, down0, out, 1.f / (96.f * 512.f * 512.f));
    // level 1: R=4 -> 96*64 strips
    lap_slide<256, 4, false, 4><<<96 * 64 / 4, 256, 0, stream>>>(
        down0, nullptr, down1, out, 1.f / (96.f * 256.f * 256.f));
    // level 2: R=2 -> 96*64 strips
    lap_slide<128, 2, false, 2><<<96 * 64 / 4, 256, 0, stream>>>(
        down1, nullptr, down2, out, 1.f / (96.f * 128.f * 128.f));
    // levels 3+4
    lap_small<<<BC, 1024, 0, stream>>>(
        down2, out, 1.f / (96.f * 64.f * 64.f), 1.f / (96.f * 32.f * 32.f));
}